// Round 2
// baseline (284.807 us; speedup 1.0000x reference)
//
#include <hip/hip_runtime.h>
#include <math.h>

#define GSZ 52
#define NA 3
#define NCLS 80
#define CH 85                    // 5 + NCLS
#define NCA (GSZ*GSZ*NA)         // 8112 cell-anchors per batch
#define MAXGT 64
#define RPB 48                   // records per k_tp block (8112 % 48 == 0 -> no batch straddle)
#define FPB (RPB*CH)             // 4080 floats staged per block
#define F4PB (FPB/4)             // 1020 float4
#define MCHUNK 32                // k_main: 32 blocks x 256 threads = 8192 >= 8112

__device__ __forceinline__ float softplusf(float x) {
    return log1pf(expf(-fabsf(x))) + fmaxf(x, 0.0f);
}

__global__ void k_init(int* cnt, int B) {
    if (threadIdx.x < B) cnt[threadIdx.x] = 0;
}

// Fused coalesced pass over targets AND preds.
// Phase T: stage 48 target records -> GT list append (conf>0).
// Phase P: stage 48 pred records  -> decoded box + conf logit compact SoA.
__global__ void k_tp(const float* __restrict__ tg, const float* __restrict__ pr,
                     const float* __restrict__ anchors, int* cnt,
                     float4* __restrict__ gtbox, int2* __restrict__ gtinfo,
                     float4* __restrict__ boxout, float* __restrict__ confout) {
    __shared__ float s[FPB];
    int tid = threadIdx.x;
    size_t rec0 = (size_t)blockIdx.x * RPB;
    int b = (int)(rec0 / NCA);
    int nloc0 = (int)(rec0 - (size_t)b * NCA);

    // ---- phase T: stage targets chunk (coalesced float4, hand-unrolled for MLP) ----
    {
        const float4* src = (const float4*)(tg + rec0 * CH);
        float4* sd = (float4*)s;
        bool g3 = (tid + 768) < F4PB;
        float4 v0 = src[tid];
        float4 v1 = src[tid + 256];
        float4 v2 = src[tid + 512];
        float4 v3 = g3 ? src[tid + 768] : make_float4(0.f, 0.f, 0.f, 0.f);
        sd[tid] = v0; sd[tid + 256] = v1; sd[tid + 512] = v2;
        if (g3) sd[tid + 768] = v3;
    }
    __syncthreads();
    if (tid < RPB) {
        const float* r = s + tid * CH;
        float conf = r[4];
        if (conf > 0.0f) {
            int cid = 0;
            for (int c = 0; c < NCLS; c++) if (r[5 + c] > 0.5f) cid = c;
            int pos = atomicAdd(cnt + b, 1);
            if (pos < MAXGT) {
                gtbox[b * MAXGT + pos] = make_float4(r[0], r[1], r[2], r[3]);
                gtinfo[b * MAXGT + pos] = make_int2(nloc0 + tid, cid);
            }
        }
    }
    __syncthreads();

    // ---- phase P: stage preds chunk (reuse LDS) ----
    {
        const float4* src = (const float4*)(pr + rec0 * CH);
        float4* sd = (float4*)s;
        bool g3 = (tid + 768) < F4PB;
        float4 v0 = src[tid];
        float4 v1 = src[tid + 256];
        float4 v2 = src[tid + 512];
        float4 v3 = g3 ? src[tid + 768] : make_float4(0.f, 0.f, 0.f, 0.f);
        sd[tid] = v0; sd[tid + 256] = v1; sd[tid + 512] = v2;
        if (g3) sd[tid + 768] = v3;
    }
    __syncthreads();
    if (tid < RPB) {
        const float* r = s + tid * CH;
        int nloc = nloc0 + tid;
        int a    = nloc % NA;
        int cell = nloc / NA;
        int gi = cell / GSZ, gj = cell % GSZ;
        float sx = 1.0f / (1.0f + expf(-r[0]));
        float sy = 1.0f / (1.0f + expf(-r[1]));
        float ew = expf(r[2]), eh = expf(r[3]);
        float aw = anchors[2 * a], ah = anchors[2 * a + 1];
        boxout[rec0 + tid] = make_float4((sx + (float)gj) * 8.0f,
                                         (sy + (float)gi) * 8.0f,
                                         ew * aw, eh * ah);
        confout[rec0 + tid] = r[4];
    }
}

// Per cell-anchor: coalesced compact reads, GT list in LDS, IoU + 5 losses.
__global__ void k_main(const float* __restrict__ pr,
                       const float* __restrict__ anchors,
                       const int* __restrict__ cnt,
                       const float4* __restrict__ gtbox,
                       const int2* __restrict__ gtinfo,
                       const float4* __restrict__ boxin,
                       const float* __restrict__ confin,
                       float* __restrict__ partial) {
    __shared__ float4 sbox[MAXGT];
    __shared__ int2   sinfo[MAXGT];
    __shared__ float  swsum[4 * 5];

    int b   = blockIdx.y;
    int tid = threadIdx.x;
    int n   = blockIdx.x * 256 + tid;

    int m = min(cnt[b], MAXGT);
    if (tid < MAXGT && tid < m) {
        sbox[tid]  = gtbox[b * MAXGT + tid];
        sinfo[tid] = gtinfo[b * MAXGT + tid];
    }
    __syncthreads();

    float v_txty = 0.f, v_twth = 0.f, v_noobj = 0.f, v_obj = 0.f, v_cls = 0.f;

    if (n < NCA) {
        size_t rec = (size_t)b * NCA + n;
        float4 pb = boxin[rec];
        float  pc = confin[rec];
        float areap = pb.z * pb.w;

        float best = 0.0f;
        int kobj = -1;
        for (int k = 0; k < m; k++) {
            float4 g = sbox[k];
            if (sinfo[k].x == n) kobj = k;
            float ix = fminf(pb.x + pb.z * 0.5f, g.x + g.z * 0.5f)
                     - fmaxf(pb.x - pb.z * 0.5f, g.x - g.z * 0.5f);
            float iy = fminf(pb.y + pb.w * 0.5f, g.y + g.w * 0.5f)
                     - fmaxf(pb.y - pb.w * 0.5f, g.y - g.w * 0.5f);
            ix = fmaxf(ix, 0.0f);
            iy = fmaxf(iy, 0.0f);
            float inter = ix * iy;
            float iou = inter / (areap + g.z * g.w - inter + 1e-9f);
            best = fmaxf(best, iou);
        }

        if (kobj >= 0) {
            float4 g = sbox[kobj];
            int a2   = n % NA;
            int cell = n / NA;
            int gi = cell / GSZ, gj = cell % GSZ;
            float aw = anchors[2 * a2], ah = anchors[2 * a2 + 1];

            float sx = pb.x * 0.125f - (float)gj;
            float sy = pb.y * 0.125f - (float)gi;
            float scale = 2.0f - (g.z / 416.0f) * (g.w / 416.0f);
            float dx = sx - (g.x * 0.125f - (float)gj);
            float dy = sy - (g.y * 0.125f - (float)gi);
            v_txty = (dx * dx + dy * dy) * scale;

            float twr = g.z / aw;  if (twr == 0.0f) twr = 1.0f;
            float thr = g.w / ah;  if (thr == 0.0f) thr = 1.0f;
            float pwr = pb.z / aw; if (pwr == 0.0f) pwr = 1.0f;
            float phr = pb.w / ah; if (phr == 0.0f) phr = 1.0f;
            twr = fminf(fmaxf(twr, 1e-9f), 1e9f);
            thr = fminf(fmaxf(thr, 1e-9f), 1e9f);
            pwr = fminf(fmaxf(pwr, 1e-9f), 1e9f);
            phr = fminf(fmaxf(phr, 1e-9f), 1e9f);
            float dw = logf(pwr) - logf(twr);
            float dh = logf(phr) - logf(thr);
            v_twth = (dw * dw + dh * dh) * scale;

            v_obj = softplusf(pc) - pc;

            const float* cl = pr + rec * CH + 5;
            float cls = 0.f;
            for (int c = 0; c < NCLS; c++) cls += softplusf(cl[c]);
            cls -= cl[sinfo[kobj].y];
            v_cls = cls;
        } else if (best < 0.6f) {
            v_noobj = softplusf(pc);
        }
    }

    float vals[5] = {v_txty, v_twth, v_noobj, v_obj, v_cls};
    int lane = tid & 63;
    int wave = tid >> 6;
#pragma unroll
    for (int i = 0; i < 5; i++) {
        float v = vals[i];
        for (int off = 32; off > 0; off >>= 1) v += __shfl_down(v, off);
        if (lane == 0) swsum[wave * 5 + i] = v;
    }
    __syncthreads();
    if (tid == 0) {
        int bid = blockIdx.y * gridDim.x + blockIdx.x;
#pragma unroll
        for (int i = 0; i < 5; i++) {
            partial[bid * 5 + i] =
                swsum[i] + swsum[5 + i] + swsum[10 + i] + swsum[15 + i];
        }
    }
}

__global__ void k_final(const float* __restrict__ partial, int nblocks, int B,
                        float* __restrict__ out) {
    __shared__ double sred[4 * 5];
    int tid = threadIdx.x;
    double acc[5] = {0, 0, 0, 0, 0};
    for (int idx = tid; idx < nblocks; idx += 256) {
#pragma unroll
        for (int i = 0; i < 5; i++) acc[i] += (double)partial[idx * 5 + i];
    }
    int lane = tid & 63;
    int wave = tid >> 6;
#pragma unroll
    for (int i = 0; i < 5; i++) {
        double v = acc[i];
        for (int off = 32; off > 0; off >>= 1) v += __shfl_down(v, off);
        if (lane == 0) sred[wave * 5 + i] = v;
    }
    __syncthreads();
    if (tid == 0) {
        double tot = 0.0;
#pragma unroll
        for (int i = 0; i < 5; i++) {
            double r = (sred[i] + sred[5 + i] + sred[10 + i] + sred[15 + i]) / (double)B;
            out[i] = (float)r;
            tot += r;
        }
        out[5] = (float)tot;
    }
}

extern "C" void kernel_launch(void* const* d_in, const int* in_sizes, int n_in,
                              void* d_out, int out_size, void* d_ws, size_t ws_size,
                              hipStream_t stream) {
    const float* preds   = (const float*)d_in[0];
    const float* targets = (const float*)d_in[1];
    const float* anchors = (const float*)d_in[2];
    float* out = (float*)d_out;

    int B = in_sizes[0] / (NCA * CH);        // 32
    size_t total_rec = (size_t)B * NCA;      // 259584
    int tp_blocks = (int)(total_rec / RPB);  // 5408
    int nblocks = MCHUNK * B;                // 1024 k_main blocks

    // ws layout (small/critical first): cnt | gtbox | gtinfo | partial | boxout | confout
    char* ws = (char*)d_ws;
    size_t off = 0;
    int*    cnt     = (int*)(ws + off);      off += 128;
    float4* gtbox   = (float4*)(ws + off);   off += (size_t)B * MAXGT * sizeof(float4);
    int2*   gtinfo  = (int2*)(ws + off);     off += (size_t)B * MAXGT * sizeof(int2);
    float*  partial = (float*)(ws + off);    off += (size_t)nblocks * 5 * sizeof(float);
    off = (off + 15) & ~(size_t)15;
    float4* boxout  = (float4*)(ws + off);   off += total_rec * sizeof(float4);
    float*  confout = (float*)(ws + off);    off += total_rec * sizeof(float);

    k_init<<<1, 64, 0, stream>>>(cnt, B);
    k_tp<<<tp_blocks, 256, 0, stream>>>(targets, preds, anchors, cnt,
                                        gtbox, gtinfo, boxout, confout);
    dim3 grid(MCHUNK, B);
    k_main<<<grid, 256, 0, stream>>>(preds, anchors, cnt, gtbox, gtinfo,
                                     boxout, confout, partial);
    k_final<<<1, 256, 0, stream>>>(partial, nblocks, B, out);
}

// Round 3
// 213.472 us; speedup vs baseline: 1.3342x; 1.3342x over previous
//
#include <hip/hip_runtime.h>
#include <math.h>

#define GSZ 52
#define NA 3
#define NCLS 80
#define CH 85                    // 5 + NCLS
#define NCA (GSZ*GSZ*NA)         // 8112 cell-anchors per batch
#define MAXGT 64
#define RPB 32                   // records per k_tp block
#define FPT (RPB*CH)             // 2720 floats per staged tensor chunk
#define F4PT (FPT/4)             // 680 float4
#define MCHUNK 32                // k_main: 32 x 256 = 8192 >= 8112

// fast softplus: max(x,0) + log(1+exp(-|x|)) with HW-approx exp/log.
// abs error ~1e-6/term; output threshold is ~1617 -> huge headroom.
__device__ __forceinline__ float softplus_fast(float x) {
    return fmaxf(x, 0.0f) + __logf(1.0f + __expf(-fabsf(x)));
}

__global__ void k_init(int* cnt, int B) {
    if (threadIdx.x < B) cnt[threadIdx.x] = 0;
}

// Coalesced staging pass: stage 32 records of targets AND preds into LDS with
// ONE barrier, then disjoint thread groups extract GT boxes (targets) and
// decode boxes (preds) concurrently.
__global__ void k_tp(const float* __restrict__ tg, const float* __restrict__ pr,
                     const float* __restrict__ anchors, int* cnt,
                     float4* __restrict__ gtbox, int2* __restrict__ gtinfo,
                     float4* __restrict__ boxout, float* __restrict__ confout) {
    __shared__ float sT[FPT];
    __shared__ float sP[FPT];
    int tid = threadIdx.x;
    size_t rec0 = (size_t)blockIdx.x * RPB;

    {
        const float4* srcT = (const float4*)(tg + rec0 * CH);
        const float4* srcP = (const float4*)(pr + rec0 * CH);
        float4* dT = (float4*)sT;
        float4* dP = (float4*)sP;
        for (int i = tid; i < F4PT; i += 256) {
            dT[i] = srcT[i];
            dP[i] = srcP[i];
        }
    }
    __syncthreads();

    if (tid < RPB) {
        // GT extraction from targets
        const float* r = sT + tid * CH;          // stride 85: conflict-free (gcd(85,32)=1)
        float conf = r[4];
        if (conf > 0.0f) {
            size_t glob = rec0 + tid;
            int b    = (int)(glob / NCA);
            int nloc = (int)(glob - (size_t)b * NCA);
            int cid = 0;
            for (int c = 0; c < NCLS; c++) if (r[5 + c] > 0.5f) cid = c;
            int pos = atomicAdd(cnt + b, 1);
            if (pos < MAXGT) {
                gtbox[b * MAXGT + pos]  = make_float4(r[0], r[1], r[2], r[3]);
                gtinfo[b * MAXGT + pos] = make_int2(nloc, cid);
            }
        }
    } else if (tid >= 64 && tid < 64 + RPB) {
        // box decode from preds
        int t = tid - 64;
        const float* r = sP + t * CH;
        size_t glob = rec0 + t;
        int b    = (int)(glob / NCA);
        int nloc = (int)(glob - (size_t)b * NCA);
        int a    = nloc % NA;
        int cell = nloc / NA;
        int gi = cell / GSZ, gj = cell % GSZ;
        float sx = __builtin_amdgcn_rcpf(1.0f + __expf(-r[0]));
        float sy = __builtin_amdgcn_rcpf(1.0f + __expf(-r[1]));
        float ew = __expf(r[2]), eh = __expf(r[3]);
        float aw = anchors[2 * a], ah = anchors[2 * a + 1];
        boxout[glob] = make_float4((sx + (float)gj) * 8.0f,
                                   (sy + (float)gi) * 8.0f,
                                   ew * aw, eh * ah);
        confout[glob] = r[4];
    }
}

// Slim noobj kernel: IoU loop (rcp instead of IEEE div) + fast softplus.
__global__ void k_main(const int* __restrict__ cnt,
                       const float4* __restrict__ gtbox,
                       const int2* __restrict__ gtinfo,
                       const float4* __restrict__ boxin,
                       const float* __restrict__ confin,
                       float* __restrict__ partial) {
    __shared__ float4 sbox[MAXGT];
    __shared__ int    sidx[MAXGT];
    __shared__ float  swsum[4];

    int b   = blockIdx.y;
    int tid = threadIdx.x;
    int n   = blockIdx.x * 256 + tid;

    int m = min(cnt[b], MAXGT);
    if (tid < m) {
        sbox[tid] = gtbox[b * MAXGT + tid];
        sidx[tid] = gtinfo[b * MAXGT + tid].x;
    }
    __syncthreads();

    float v = 0.0f;
    if (n < NCA) {
        size_t rec = (size_t)b * NCA + n;
        float4 pb = boxin[rec];
        float  pc = confin[rec];
        float px0 = pb.x - pb.z * 0.5f, px1 = pb.x + pb.z * 0.5f;
        float py0 = pb.y - pb.w * 0.5f, py1 = pb.y + pb.w * 0.5f;
        float areap = pb.z * pb.w;

        float best = 0.0f;
        bool isobj = false;
        for (int k = 0; k < m; k++) {
            float4 g = sbox[k];
            isobj |= (sidx[k] == n);
            float ix = fminf(px1, g.x + g.z * 0.5f) - fmaxf(px0, g.x - g.z * 0.5f);
            float iy = fminf(py1, g.y + g.w * 0.5f) - fmaxf(py0, g.y - g.w * 0.5f);
            float inter = fmaxf(ix, 0.0f) * fmaxf(iy, 0.0f);
            float u = areap + g.z * g.w - inter + 1e-9f;
            best = fmaxf(best, inter * __builtin_amdgcn_rcpf(u));
        }
        if (!isobj && best < 0.6f) v = softplus_fast(pc);
    }

    int lane = tid & 63;
    int wv   = tid >> 6;
    for (int off = 32; off > 0; off >>= 1) v += __shfl_down(v, off);
    if (lane == 0) swsum[wv] = v;
    __syncthreads();
    if (tid == 0) {
        int bid = blockIdx.y * gridDim.x + blockIdx.x;
        partial[bid] = swsum[0] + swsum[1] + swsum[2] + swsum[3];
    }
}

// Obj-cell losses: one wave per GT slot, lanes cover the 80 classes.
__global__ void k_cls(const float* __restrict__ pr,
                      const float* __restrict__ anchors,
                      const int* __restrict__ cnt,
                      const float4* __restrict__ gtbox,
                      const int2* __restrict__ gtinfo,
                      const float4* __restrict__ boxin,
                      const float* __restrict__ confin,
                      float4* __restrict__ cls4) {
    int tid  = threadIdx.x;
    int wv   = tid >> 6;
    int lane = tid & 63;
    int slot = blockIdx.x * 4 + wv;        // 0 .. B*MAXGT-1
    int b = slot >> 6;                     // / MAXGT
    int k = slot & (MAXGT - 1);

    float4 resv = make_float4(0.f, 0.f, 0.f, 0.f);
    int m = min(cnt[b], MAXGT);
    if (k < m) {
        float4 g  = gtbox[slot];
        int2 info = gtinfo[slot];
        int n = info.x, cid = info.y;
        size_t rec = (size_t)b * NCA + n;
        const float* cl = pr + rec * CH + 5;

        float x0 = cl[lane];
        float cls = softplus_fast(x0) - (lane == cid ? x0 : 0.0f);
        if (lane < NCLS - 64) {
            float x1 = cl[64 + lane];
            cls += softplus_fast(x1) - ((64 + lane) == cid ? x1 : 0.0f);
        }
        for (int off = 32; off > 0; off >>= 1) cls += __shfl_down(cls, off);

        if (lane == 0) {
            float4 pb = boxin[rec];
            float  pc = confin[rec];
            int a    = n % NA;
            int cell = n / NA;
            int gi = cell / GSZ, gj = cell % GSZ;
            float aw = anchors[2 * a], ah = anchors[2 * a + 1];

            float scale = 2.0f - (g.z * (1.0f / 416.0f)) * (g.w * (1.0f / 416.0f));
            float dx = (pb.x * 0.125f - (float)gj) - (g.x * 0.125f - (float)gj);
            float dy = (pb.y * 0.125f - (float)gi) - (g.y * 0.125f - (float)gi);
            float txty = (dx * dx + dy * dy) * scale;

            float rw = __builtin_amdgcn_rcpf(aw), rh = __builtin_amdgcn_rcpf(ah);
            float pwr = fminf(fmaxf(pb.z * rw, 1e-9f), 1e9f);
            float phr = fminf(fmaxf(pb.w * rh, 1e-9f), 1e9f);
            float twr = fminf(fmaxf(g.z  * rw, 1e-9f), 1e9f);
            float thr = fminf(fmaxf(g.w  * rh, 1e-9f), 1e9f);
            float dw = __logf(pwr) - __logf(twr);
            float dh = __logf(phr) - __logf(thr);
            float twth = (dw * dw + dh * dh) * scale;

            float obj = softplus_fast(pc) - pc;
            resv = make_float4(txty, twth, obj, cls);
        }
    }
    if (lane == 0) cls4[slot] = resv;
}

__global__ void k_final(const float* __restrict__ partial, int np,
                        const float4* __restrict__ cls4, int ns,
                        int B, float* __restrict__ out) {
    __shared__ double sred[4 * 5];
    int tid = threadIdx.x;
    double acc[5] = {0, 0, 0, 0, 0};   // txty, twth, noobj, obj, cls
    for (int i = tid; i < np; i += 256) acc[2] += (double)partial[i];
    for (int i = tid; i < ns; i += 256) {
        float4 v = cls4[i];
        acc[0] += (double)v.x; acc[1] += (double)v.y;
        acc[3] += (double)v.z; acc[4] += (double)v.w;
    }
    int lane = tid & 63;
    int wv   = tid >> 6;
#pragma unroll
    for (int i = 0; i < 5; i++) {
        double v = acc[i];
        for (int off = 32; off > 0; off >>= 1) v += __shfl_down(v, off);
        if (lane == 0) sred[wv * 5 + i] = v;
    }
    __syncthreads();
    if (tid == 0) {
        double tot = 0.0;
#pragma unroll
        for (int i = 0; i < 5; i++) {
            double r = (sred[i] + sred[5 + i] + sred[10 + i] + sred[15 + i]) / (double)B;
            out[i] = (float)r;
            tot += r;
        }
        out[5] = (float)tot;
    }
}

extern "C" void kernel_launch(void* const* d_in, const int* in_sizes, int n_in,
                              void* d_out, int out_size, void* d_ws, size_t ws_size,
                              hipStream_t stream) {
    const float* preds   = (const float*)d_in[0];
    const float* targets = (const float*)d_in[1];
    const float* anchors = (const float*)d_in[2];
    float* out = (float*)d_out;

    int B = in_sizes[0] / (NCA * CH);        // 32
    size_t total_rec = (size_t)B * NCA;      // 259584
    int tp_blocks = (int)(total_rec / RPB);  // 8112
    int np = MCHUNK * B;                     // 1024
    int ns = B * MAXGT;                      // 2048

    // ws layout: cnt | gtbox | gtinfo | partial | cls4 | boxout | confout
    char* ws = (char*)d_ws;
    size_t off = 0;
    int*    cnt     = (int*)(ws + off);      off += 128;
    float4* gtbox   = (float4*)(ws + off);   off += (size_t)ns * sizeof(float4);
    int2*   gtinfo  = (int2*)(ws + off);     off += (size_t)ns * sizeof(int2);
    float*  partial = (float*)(ws + off);    off += (size_t)np * sizeof(float);
    off = (off + 15) & ~(size_t)15;
    float4* cls4    = (float4*)(ws + off);   off += (size_t)ns * sizeof(float4);
    float4* boxout  = (float4*)(ws + off);   off += total_rec * sizeof(float4);
    float*  confout = (float*)(ws + off);    off += total_rec * sizeof(float);

    k_init<<<1, 64, 0, stream>>>(cnt, B);
    k_tp<<<tp_blocks, 256, 0, stream>>>(targets, preds, anchors, cnt,
                                        gtbox, gtinfo, boxout, confout);
    dim3 grid(MCHUNK, B);
    k_main<<<grid, 256, 0, stream>>>(cnt, gtbox, gtinfo, boxout, confout, partial);
    k_cls<<<ns / 4, 256, 0, stream>>>(preds, anchors, cnt, gtbox, gtinfo,
                                      boxout, confout, cls4);
    k_final<<<1, 256, 0, stream>>>(partial, np, cls4, ns, B, out);
}